// Round 3
// baseline (250.223 us; speedup 1.0000x reference)
//
#include <hip/hip_runtime.h>
#include <hip/hip_bf16.h>

typedef __bf16 bf16_t;
typedef _Float16 f16_t;
typedef bf16_t bf16x8 __attribute__((ext_vector_type(8)));
typedef f16_t  f16x8  __attribute__((ext_vector_type(8)));
typedef f16_t  f16x4  __attribute__((ext_vector_type(4)));
typedef float  floatx4 __attribute__((ext_vector_type(4)));
typedef float  floatx16 __attribute__((ext_vector_type(16)));
typedef bf16x8 bf16x8u __attribute__((aligned(8)));

#define DEV static __device__ __forceinline__

DEV floatx4 mfma16_bf16(bf16x8 a, bf16x8 b, floatx4 c) {
  return __builtin_amdgcn_mfma_f32_16x16x32_bf16(a, b, c, 0, 0, 0);
}
DEV floatx16 mfma32_bf16(bf16x8 a, bf16x8 b, floatx16 c) {
  return __builtin_amdgcn_mfma_f32_32x32x16_bf16(a, b, c, 0, 0, 0);
}
DEV floatx16 mfma32x8_f16(f16x4 a, f16x4 b, floatx16 c) {
  return __builtin_amdgcn_mfma_f32_32x32x8f16(a, b, c, 0, 0, 0);
}
DEV void async_ld16(void* lds, const void* g) {
  __builtin_amdgcn_global_load_lds(
      (const __attribute__((address_space(1))) unsigned int*)g,
      (__attribute__((address_space(3))) unsigned int*)lds, 16, 0, 0);
}

// ---------------------------------------------------------------------------
// Prep: split+transpose all 4 weights to bf16 hi/lo [n][k] (+lo at +16384),
// and gather t2.
// ---------------------------------------------------------------------------
__global__ void prep_kernel(const float* __restrict__ Wk1, const float* __restrict__ Wk2,
                            const float* __restrict__ Wv1, const float* __restrict__ Wv2,
                            const float* __restrict__ X,
                            bf16_t* __restrict__ W1p, bf16_t* __restrict__ W2p,
                            bf16_t* __restrict__ W3p, bf16_t* __restrict__ W4p,
                            float* __restrict__ t2pre) {
  int b = blockIdx.x;
  if (b < 16) {
    int m = b >> 2, p = b & 3;
    const float* src = m == 0 ? Wk1 : m == 1 ? Wk2 : m == 2 ? Wv1 : Wv2;
    bf16_t* dst = m == 0 ? W1p : m == 1 ? W2p : m == 2 ? W3p : W4p;
    for (int u = 0; u < 16; ++u) {
      int idx = p * 4096 + u * 256 + threadIdx.x;   // k*128 + n
      int k = idx >> 7, nn = idx & 127;
      float v = src[idx];
      int o = nn * 128 + k;
      bf16_t h = (bf16_t)v;
      dst[o] = h;
      dst[16384 + o] = (bf16_t)(v - (float)h);
    }
  } else {
    int i = (b - 16) * 256 + threadIdx.x;           // n*1024 + l
    t2pre[i] = X[((size_t)(i >> 10) * 8192 + (i & 1023)) * 128 + 127];
  }
}

// ---------------------------------------------------------------------------
// MLP-K: split-bf16, 64 rows/block, double-buffered weight staging (8 phases,
// 1 barrier each; phase p+1 prefetched under phase p compute).
// ---------------------------------------------------------------------------
__global__ __launch_bounds__(256) void mlp_k_kernel(
    const float* __restrict__ X, const float* __restrict__ b1,
    const float* __restrict__ b2, const bf16_t* __restrict__ W1p,
    const bf16_t* __restrict__ W2p, bf16_t* __restrict__ Khi,
    bf16_t* __restrict__ Klo) {
  __shared__ __align__(16) char sXbuf[2 * 16896];
  __shared__ __align__(16) bf16_t sW[2][256 * 40];
  bf16_t* sXh = (bf16_t*)sXbuf;
  bf16_t* sXl = sXh + 64 * 132;

  const int tid = threadIdx.x, lane = tid & 63, wave = tid >> 6;
  const int q = lane >> 4, c15 = lane & 15;
  const size_t rowBase = (size_t)blockIdx.x * 64;

  int goff[5];
  for (int a = 0; a < 5; ++a) {
    int o = (wave + 4 * a) * 1024 + lane * 16;
    int row = o / 80, rem = o % 80;
    goff[a] = row * 256 + (rem < 64 ? rem : 0);
  }
  float b1v[8], b2v[8];
  for (int nt = 0; nt < 8; ++nt) { b1v[nt] = b1[nt * 16 + c15]; b2v[nt] = b2[nt * 16 + c15]; }

  // X -> hi/lo bf16
  for (int u = 0; u < 8; ++u) {
    int idx = tid + u * 256;
    int r = idx >> 5, c4 = (idx & 31) << 2;
    float4 v = *(const float4*)(X + (rowBase + r) * 128 + c4);
    int o = r * 132 + c4;
    float vv[4] = {v.x, v.y, v.z, v.w};
    for (int i = 0; i < 4; ++i) {
      bf16_t h = (bf16_t)vv[i];
      sXh[o + i] = h;
      sXl[o + i] = (bf16_t)(vv[i] - (float)h);
    }
  }

  auto issueW = [&](int buf, int ph) {
    const bf16_t* Wp = (ph < 4) ? W1p : W2p;
    const char* base = (const char*)Wp + (ph & 3) * 64;
    for (int a = 0; a < 5; ++a)
      async_ld16((char*)sW[buf] + (wave + 4 * a) * 1024 + lane * 16, base + goff[a]);
  };

  floatx4 acc1[8], acc2[8];
  for (int i = 0; i < 8; ++i) { acc1[i] = {}; acc2[i] = {}; }

  issueW(0, 0);
  __syncthreads();
#pragma unroll
  for (int ph = 0; ph < 8; ++ph) {
    if (ph < 7) issueW((ph + 1) & 1, ph + 1);
    const bf16_t* wb = sW[ph & 1];
    const int kq = ph & 3;
    floatx4* acc = (ph < 4) ? acc1 : acc2;
    const int ao = (wave * 16 + c15) * 132 + kq * 32 + q * 8;
    bf16x8 ah = *(const bf16x8u*)(sXh + ao);
    bf16x8 al = *(const bf16x8u*)(sXl + ao);
    for (int nt = 0; nt < 8; ++nt) {
      const int bo = (nt * 16 + c15) * 40 + q * 8;
      bf16x8 bh = *(const bf16x8*)(wb + bo);
      bf16x8 bl = *(const bf16x8*)(wb + 128 * 40 + bo);
      acc[nt] = mfma16_bf16(ah, bh, acc[nt]);
      acc[nt] = mfma16_bf16(ah, bl, acc[nt]);
      acc[nt] = mfma16_bf16(al, bh, acc[nt]);
    }
    if (ph == 3) {
      // H = relu(acc1+b1) -> sX hi/lo (own rows)
      for (int nt = 0; nt < 8; ++nt)
        for (int r = 0; r < 4; ++r) {
          float h = fmaxf(acc1[nt][r] + b1v[nt], 0.f);
          bf16_t hh = (bf16_t)h;
          int o = (wave * 16 + q * 4 + r) * 132 + nt * 16 + c15;
          sXh[o] = hh;
          sXl[o] = (bf16_t)(h - (float)hh);
        }
    }
    __syncthreads();
  }

  // epilogue: K hi/lo -> sX (own rows) -> coalesced copy-out
  for (int nt = 0; nt < 8; ++nt)
    for (int r = 0; r < 4; ++r) {
      float kv = acc2[nt][r] + b2v[nt];
      bf16_t kh = (bf16_t)kv;
      int o = (wave * 16 + q * 4 + r) * 132 + nt * 16 + c15;
      sXh[o] = kh;
      sXl[o] = (bf16_t)(kv - (float)kh);
    }
  __syncthreads();
  for (int u = 0; u < 4; ++u) {
    int idx = tid + u * 256;
    int r = idx >> 4, c8 = (idx & 15) << 3;
    bf16x8 vh = *(const bf16x8u*)(sXh + r * 132 + c8);
    bf16x8 vl = *(const bf16x8u*)(sXl + r * 132 + c8);
    *(bf16x8*)(Khi + (rowBase + r) * 128 + c8) = vh;
    *(bf16x8*)(Klo + (rowBase + r) * 128 + c8) = vl;
  }
}

// ---------------------------------------------------------------------------
// MLP-V: split-bf16 both stages; stage 2 emits V^T (f16) directly.
// ---------------------------------------------------------------------------
__global__ __launch_bounds__(256) void mlp_v_kernel(
    const float* __restrict__ X, const float* __restrict__ b1,
    const float* __restrict__ b2, const bf16_t* __restrict__ W1p,
    const bf16_t* __restrict__ W2p, f16_t* __restrict__ Vt) {
  __shared__ __align__(16) char sXbuf[2 * 16896];
  __shared__ __align__(16) bf16_t sW[2][256 * 40];
  bf16_t* sXh = (bf16_t*)sXbuf;
  bf16_t* sXl = sXh + 64 * 132;

  const int tid = threadIdx.x, lane = tid & 63, wave = tid >> 6;
  const int q = lane >> 4, c15 = lane & 15;
  const size_t rowBase = (size_t)blockIdx.x * 64;

  int goff[5];
  for (int a = 0; a < 5; ++a) {
    int o = (wave + 4 * a) * 1024 + lane * 16;
    int row = o / 80, rem = o % 80;
    goff[a] = row * 256 + (rem < 64 ? rem : 0);
  }
  float b1v[8], bvv[2][4];
  for (int nt = 0; nt < 8; ++nt) b1v[nt] = b1[nt * 16 + c15];
  for (int mt = 0; mt < 2; ++mt)
    for (int r = 0; r < 4; ++r)
      bvv[mt][r] = b2[(wave * 2 + mt) * 16 + q * 4 + r];

  for (int u = 0; u < 8; ++u) {
    int idx = tid + u * 256;
    int r = idx >> 5, c4 = (idx & 31) << 2;
    float4 v = *(const float4*)(X + (rowBase + r) * 128 + c4);
    int o = r * 132 + c4;
    float vv[4] = {v.x, v.y, v.z, v.w};
    for (int i = 0; i < 4; ++i) {
      bf16_t h = (bf16_t)vv[i];
      sXh[o + i] = h;
      sXl[o + i] = (bf16_t)(vv[i] - (float)h);
    }
  }

  auto issueW = [&](int buf, int ph) {
    const bf16_t* Wp = (ph < 4) ? W1p : W2p;
    const char* base = (const char*)Wp + (ph & 3) * 64;
    for (int a = 0; a < 5; ++a)
      async_ld16((char*)sW[buf] + (wave + 4 * a) * 1024 + lane * 16, base + goff[a]);
  };

  floatx4 acc1[8], acc2[2][4];
  for (int i = 0; i < 8; ++i) acc1[i] = {};
  for (int i = 0; i < 2; ++i) for (int j = 0; j < 4; ++j) acc2[i][j] = {};

  issueW(0, 0);
  __syncthreads();
#pragma unroll
  for (int ph = 0; ph < 8; ++ph) {
    if (ph < 7) issueW((ph + 1) & 1, ph + 1);
    const bf16_t* wb = sW[ph & 1];
    const int kq = ph & 3;
    if (ph < 4) {
      const int ao = (wave * 16 + c15) * 132 + kq * 32 + q * 8;
      bf16x8 ah = *(const bf16x8u*)(sXh + ao);
      bf16x8 al = *(const bf16x8u*)(sXl + ao);
      for (int nt = 0; nt < 8; ++nt) {
        const int bo = (nt * 16 + c15) * 40 + q * 8;
        bf16x8 bh = *(const bf16x8*)(wb + bo);
        bf16x8 bl = *(const bf16x8*)(wb + 128 * 40 + bo);
        acc1[nt] = mfma16_bf16(ah, bh, acc1[nt]);
        acc1[nt] = mfma16_bf16(ah, bl, acc1[nt]);
        acc1[nt] = mfma16_bf16(al, bh, acc1[nt]);
      }
      if (ph == 3) {
        for (int nt = 0; nt < 8; ++nt)
          for (int r = 0; r < 4; ++r) {
            float h = fmaxf(acc1[nt][r] + b1v[nt], 0.f);
            bf16_t hh = (bf16_t)h;
            int o = (wave * 16 + q * 4 + r) * 132 + nt * 16 + c15;
            sXh[o] = hh;
            sXl[o] = (bf16_t)(h - (float)hh);
          }
      }
    } else {
      // D[c][l] = sum_k W2t[c][k] H[l][k]: A = W2t rows (c), B = H rows (l)
      bf16x8 awh[2], awl[2];
      for (int mt = 0; mt < 2; ++mt) {
        const int aoo = ((wave * 2 + mt) * 16 + c15) * 40 + q * 8;
        awh[mt] = *(const bf16x8*)(wb + aoo);
        awl[mt] = *(const bf16x8*)(wb + 128 * 40 + aoo);
      }
      for (int nt = 0; nt < 4; ++nt) {
        const int bo = (nt * 16 + c15) * 132 + kq * 32 + q * 8;
        bf16x8 bh = *(const bf16x8u*)(sXh + bo);
        bf16x8 bl = *(const bf16x8u*)(sXl + bo);
        for (int mt = 0; mt < 2; ++mt) {
          acc2[mt][nt] = mfma16_bf16(awh[mt], bh, acc2[mt][nt]);
          acc2[mt][nt] = mfma16_bf16(awh[mt], bl, acc2[mt][nt]);
          acc2[mt][nt] = mfma16_bf16(awl[mt], bh, acc2[mt][nt]);
        }
      }
    }
    __syncthreads();
  }

  // V^T tile (c=128 rows, l=64 cols) f16 into reused sXbuf, then copy out
  f16_t* sVT = (f16_t*)sXbuf;                      // stride 72, 18432B
  for (int mt = 0; mt < 2; ++mt)
    for (int nt = 0; nt < 4; ++nt)
      for (int r = 0; r < 4; ++r) {
        int c = (wave * 2 + mt) * 16 + q * 4 + r;
        sVT[c * 72 + nt * 16 + c15] = (f16_t)(acc2[mt][nt][r] + bvv[mt][r]);
      }
  __syncthreads();
  const int nh = (int)(rowBase >> 10);
  const int lB = (int)(rowBase & 1023);
  for (int u = 0; u < 4; ++u) {
    int idx = tid + u * 256;
    int c = idx >> 3, l8 = (idx & 7) << 3;
    *(f16x8*)(Vt + ((size_t)nh * 128 + c) * 1024 + lB + l8) =
        *(const f16x8*)(sVT + c * 72 + l8);
  }
}

// ---------------------------------------------------------------------------
// attn: 32x32 register pipeline. S^T = K*Q^T (32x32x16 bf16 split, C-layout
// col=qrow) -> exp/mask in regs -> S reg-groups ARE the 32x32x8 f16 B-operand
// for O^T += V^T * P. No P LDS round-trip. 1 barrier/iter.
// ---------------------------------------------------------------------------
__global__ __launch_bounds__(256, 2) void attn_kernel(
    const float* __restrict__ Q, const float* __restrict__ t1,
    const float* __restrict__ t2pre, const float* __restrict__ ltau,
    const bf16_t* __restrict__ Khi, const bf16_t* __restrict__ Klo,
    const f16_t* __restrict__ Vt, float* __restrict__ out) {
  __shared__ __align__(16) char sBuf[2][27648];    // [K hi/lo 17408 | V^T 10240]
  __shared__ __align__(16) float sT2[1024];

  const int tid = threadIdx.x, lane = tid & 63, wave = tid >> 6;
  const int h = lane >> 5, l31 = lane & 31;
  const int nh = blockIdx.x & 63;                  // 8 T-blocks of a head share XCD
  const int tB = (blockIdx.x >> 6) << 7;
  const int n = nh >> 3;
  const int qrow = tB + wave * 32 + l31;
  const float c2 = __expf(-ltau[0]) * 1.44269504f;

  // staging slot map (27 chunks of 1KB: K 17 + V 10)
  const char* gp[7]; int ls[7]; int st[7];
  for (int a = 0; a < 7; ++a) {
    int j = wave + 4 * a;
    gp[a] = nullptr; ls[a] = 0; st[a] = 0;
    if (j < 17) {
      int o = j * 1024 + lane * 16;
      int half = o >= 8704 ? 1 : 0;
      int r2 = o - half * 8704;
      int row = r2 / 272, rem = r2 % 272;
      if (rem >= 256) rem = 0;
      gp[a] = (const char*)(half ? Klo : Khi) + ((size_t)((nh << 10) + row)) * 256 + rem;
      st[a] = 8192; ls[a] = o;
    } else if (j < 27) {
      int o = (j - 17) * 1024 + lane * 16;
      int c = o / 80, rem = o % 80;
      if (rem >= 64) rem = 0;
      gp[a] = (const char*)Vt + ((size_t)((nh << 7) + c)) * 2048 + rem;
      st[a] = 64; ls[a] = 17408 + o;
    }
  }
  auto stage = [&](int buf) {
    for (int a = 0; a < 7; ++a) {
      int j = wave + 4 * a;
      if (j < 27) { async_ld16(sBuf[buf] + ls[a], gp[a]); gp[a] += st[a]; }
    }
  };

  stage(0);
  *(float4*)(sT2 + tid * 4) = *(const float4*)(t2pre + (n << 10) + tid * 4);

  // Q fragments (B-operand of 32x32x16): lane holds Q[qrow][ks*16 + h*8 + j]
  bf16x8 qh[8], ql[8];
  {
    const float* qr = Q + ((size_t)(nh << 10) + qrow) * 128;
    for (int ks = 0; ks < 8; ++ks) {
      const float* p = qr + ks * 16 + h * 8;
      float4 v0 = *(const float4*)p;
      float4 v1 = *(const float4*)(p + 4);
      float vv[8] = {v0.x, v0.y, v0.z, v0.w, v1.x, v1.y, v1.z, v1.w};
      bf16x8 hi, lo;
      for (int j = 0; j < 8; ++j) {
        bf16_t hj = (bf16_t)vv[j];
        hi[j] = hj;
        lo[j] = (bf16_t)(vv[j] - (float)hj);
      }
      qh[ks] = hi;
      ql[ks] = lo;
    }
  }
  const float t1v = t1[(n << 10) + qrow];

  floatx16 O[4];
  for (int i = 0; i < 4; ++i) O[i] = {};
  float ds = 0.f;

  __syncthreads();
  for (int it = 0; it < 32; ++it) {
    const int cur = it & 1;
    if (it < 31) stage(cur ^ 1);
    const char* kb = sBuf[cur];
    const char* vb = sBuf[cur] + 17408;

    // S^T[l 32][qrow 32], l = (reg&3) + 8*(reg>>2) + 4*h
    floatx16 S = {};
    for (int ks = 0; ks < 8; ++ks) {
      const int bo = l31 * 272 + ks * 32 + h * 16;
      bf16x8 kh_ = *(const bf16x8*)(kb + bo);
      bf16x8 kl_ = *(const bf16x8*)(kb + 8704 + bo);
      S = mfma32_bf16(kh_, qh[ks], S);
      S = mfma32_bf16(kl_, qh[ks], S);
      S = mfma32_bf16(kh_, ql[ks], S);
    }

    const float* t2b = sT2 + it * 32 + h * 4;
    for (int t = 0; t < 4; ++t) {
      float4 t2v = *(const float4*)(t2b + t * 8);
      float tv[4] = {t2v.x, t2v.y, t2v.z, t2v.w};
      f16x4 pb;
      for (int j = 0; j < 4; ++j) {
        float s = S[4 * t + j];
        float e = exp2f(-s * s * c2);
        bool m = (t1v >= tv[j]);
        ds += m ? e : 1.f;
        pb[j] = (f16_t)(m ? e : 0.f);
      }
      for (int ct = 0; ct < 4; ++ct) {
        f16x4 va = *(const f16x4*)(vb + (ct * 32 + l31) * 80 + t * 16 + h * 8);
        O[ct] = mfma32x8_f16(va, pb, O[ct]);
      }
    }
    __syncthreads();
  }

  ds += __shfl_xor(ds, 32);
  const float inv = 1.f / ds;
  float* orow = out + ((size_t)(nh << 10) + qrow) * 128;
  for (int ct = 0; ct < 4; ++ct)
    for (int t = 0; t < 4; ++t) {
      int c = ct * 32 + 8 * t + 4 * h;
      float4 v = {O[ct][4 * t + 0] * inv, O[ct][4 * t + 1] * inv,
                  O[ct][4 * t + 2] * inv, O[ct][4 * t + 3] * inv};
      *(float4*)(orow + c) = v;
    }
}

extern "C" void kernel_launch(void* const* d_in, const int* in_sizes, int n_in,
                              void* d_out, int out_size, void* d_ws, size_t ws_size,
                              hipStream_t stream) {
  const float* X   = (const float*)d_in[0];
  const float* t1  = (const float*)d_in[1];
  const float* Q   = (const float*)d_in[2];
  const float* Wk1 = (const float*)d_in[3];
  const float* bk1 = (const float*)d_in[4];
  const float* Wk2 = (const float*)d_in[5];
  const float* bk2 = (const float*)d_in[6];
  const float* Wv1 = (const float*)d_in[7];
  const float* bv1 = (const float*)d_in[8];
  const float* Wv2 = (const float*)d_in[9];
  const float* bv2 = (const float*)d_in[10];
  const float* log_tau = (const float*)d_in[11];
  float* out = (float*)d_out;

  const size_t E = (size_t)64 * 1024 * 128;
  bf16_t* Khi = (bf16_t*)d_ws;
  bf16_t* Klo = Khi + E;
  f16_t*  Vt  = (f16_t*)(Klo + E);
  bf16_t* W1p = (bf16_t*)((char*)d_ws + 3 * E * 2);
  bf16_t* W2p = W1p + 32768;
  bf16_t* W3p = W2p + 32768;
  bf16_t* W4p = W3p + 32768;
  float*  t2pre = (float*)(W4p + 32768);

  prep_kernel<<<48, 256, 0, stream>>>(Wk1, Wk2, Wv1, Wv2, X, W1p, W2p, W3p, W4p, t2pre);
  mlp_k_kernel<<<1024, 256, 0, stream>>>(X, bk1, bk2, W1p, W2p, Khi, Klo);
  mlp_v_kernel<<<1024, 256, 0, stream>>>(X, bv1, bv2, W3p, W4p, Vt);
  attn_kernel<<<512, 256, 0, stream>>>(Q, t1, t2pre, log_tau, Khi, Klo, Vt, out);
}

// Round 4
// 234.949 us; speedup vs baseline: 1.0650x; 1.0650x over previous
//
#include <hip/hip_runtime.h>
#include <hip/hip_bf16.h>

typedef __bf16 bf16_t;
typedef _Float16 f16_t;
typedef bf16_t bf16x8 __attribute__((ext_vector_type(8)));
typedef f16_t  f16x8  __attribute__((ext_vector_type(8)));
typedef f16_t  f16x4  __attribute__((ext_vector_type(4)));
typedef float  floatx4 __attribute__((ext_vector_type(4)));
typedef float  floatx16 __attribute__((ext_vector_type(16)));
typedef bf16x8 bf16x8u __attribute__((aligned(8)));
typedef f16x8  f16x8u  __attribute__((aligned(8)));

#define DEV static __device__ __forceinline__

DEV floatx4 mfma16_bf16(bf16x8 a, bf16x8 b, floatx4 c) {
  return __builtin_amdgcn_mfma_f32_16x16x32_bf16(a, b, c, 0, 0, 0);
}
DEV floatx4 mfma16_f16(f16x8 a, f16x8 b, floatx4 c) {
  return __builtin_amdgcn_mfma_f32_16x16x32_f16(a, b, c, 0, 0, 0);
}
DEV floatx16 mfma32_bf16(bf16x8 a, bf16x8 b, floatx16 c) {
  return __builtin_amdgcn_mfma_f32_32x32x16_bf16(a, b, c, 0, 0, 0);
}
DEV floatx16 mfma32x8_f16(f16x4 a, f16x4 b, floatx16 c) {
  return __builtin_amdgcn_mfma_f32_32x32x8f16(a, b, c, 0, 0, 0);
}
DEV void async_ld16(void* lds, const void* g) {
  __builtin_amdgcn_global_load_lds(
      (const __attribute__((address_space(1))) unsigned int*)g,
      (__attribute__((address_space(3))) unsigned int*)lds, 16, 0, 0);
}
DEV float fast_exp2(float x) {  // v_exp_f32 = 2^x, no libm slow path
  float r;
  asm("v_exp_f32 %0, %1" : "=v"(r) : "v"(x));
  return r;
}

// ---------------------------------------------------------------------------
// Prep: LDS-transposed weight prep (coalesced stores). K weights -> bf16 hi/lo
// [n][k] (+lo at +16384 elems); V weights -> f16 [n][k]. Plus t2 gather.
// ---------------------------------------------------------------------------
__global__ void prep_kernel(const float* __restrict__ Wk1, const float* __restrict__ Wk2,
                            const float* __restrict__ Wv1, const float* __restrict__ Wv2,
                            const float* __restrict__ X,
                            bf16_t* __restrict__ W1p, bf16_t* __restrict__ W2p,
                            f16_t* __restrict__ W3f, f16_t* __restrict__ W4f,
                            float* __restrict__ t2pre) {
  int b = blockIdx.x;
  if (b < 16) {
    int m = b >> 2, p = b & 3;   // weight m, k-quarter p (rows k in [32p,32p+32))
    const float* src = m == 0 ? Wk1 : m == 1 ? Wk2 : m == 2 ? Wv1 : Wv2;
    __shared__ float tile[32][129];
    for (int u = 0; u < 4; ++u) {
      int idx = threadIdx.x + u * 256;        // 1024 float4 units
      int k = idx >> 5, n4 = (idx & 31) << 2;
      float4 v = *(const float4*)(src + (size_t)(p * 32 + k) * 128 + n4);
      tile[k][n4 + 0] = v.x; tile[k][n4 + 1] = v.y;
      tile[k][n4 + 2] = v.z; tile[k][n4 + 3] = v.w;
    }
    __syncthreads();
    if (m < 2) {
      bf16_t* dst = m ? W2p : W1p;
      for (int u = 0; u < 2; ++u) {
        int idx = threadIdx.x + u * 256;      // 512 units: n, k-chunk of 8
        int n = idx >> 2, kc = idx & 3;
        bf16x8 hi, lo;
        for (int j = 0; j < 8; ++j) {
          float v = tile[kc * 8 + j][n];
          bf16_t hh = (bf16_t)v;
          hi[j] = hh;
          lo[j] = (bf16_t)(v - (float)hh);
        }
        *(bf16x8*)(dst + n * 128 + p * 32 + kc * 8) = hi;
        *(bf16x8*)(dst + 16384 + n * 128 + p * 32 + kc * 8) = lo;
      }
    } else {
      f16_t* dst = (m == 3) ? W4f : W3f;
      for (int u = 0; u < 2; ++u) {
        int idx = threadIdx.x + u * 256;
        int n = idx >> 2, kc = idx & 3;
        f16x8 w;
        for (int j = 0; j < 8; ++j) w[j] = (f16_t)tile[kc * 8 + j][n];
        *(f16x8*)(dst + n * 128 + p * 32 + kc * 8) = w;
      }
    }
  } else {
    int i = (b - 16) * 256 + threadIdx.x;     // n*1024 + l
    t2pre[i] = X[((size_t)(i >> 10) * 8192 + (i & 1023)) * 128 + 127];
  }
}

// ---------------------------------------------------------------------------
// MLP-K: split-bf16, 64 rows/block, dbuf weight staging (8 phases).
// ---------------------------------------------------------------------------
__global__ __launch_bounds__(256) void mlp_k_kernel(
    const float* __restrict__ X, const float* __restrict__ b1,
    const float* __restrict__ b2, const bf16_t* __restrict__ W1p,
    const bf16_t* __restrict__ W2p, bf16_t* __restrict__ Khi,
    bf16_t* __restrict__ Klo) {
  __shared__ __align__(16) char sXbuf[2 * 16896];
  __shared__ __align__(16) bf16_t sW[2][256 * 40];
  bf16_t* sXh = (bf16_t*)sXbuf;
  bf16_t* sXl = sXh + 64 * 132;

  const int tid = threadIdx.x, lane = tid & 63, wave = tid >> 6;
  const int q = lane >> 4, c15 = lane & 15;
  const size_t rowBase = (size_t)blockIdx.x * 64;

  int goff[5];
  for (int a = 0; a < 5; ++a) {
    int o = (wave + 4 * a) * 1024 + lane * 16;
    int row = o / 80, rem = o % 80;
    goff[a] = row * 256 + (rem < 64 ? rem : 0);
  }
  auto issueW = [&](int buf, int ph) {
    const bf16_t* Wp = (ph < 4) ? W1p : W2p;
    const char* base = (const char*)Wp + (ph & 3) * 64;
    for (int a = 0; a < 5; ++a)
      async_ld16((char*)sW[buf] + (wave + 4 * a) * 1024 + lane * 16, base + goff[a]);
  };

  issueW(0, 0);    // prefetch W phase 0 under X conversion

  float b1v[8], b2v[8];
  for (int nt = 0; nt < 8; ++nt) { b1v[nt] = b1[nt * 16 + c15]; b2v[nt] = b2[nt * 16 + c15]; }

  for (int u = 0; u < 8; ++u) {
    int idx = tid + u * 256;
    int r = idx >> 5, c4 = (idx & 31) << 2;
    float4 v = *(const float4*)(X + (rowBase + r) * 128 + c4);
    int o = r * 132 + c4;
    float vv[4] = {v.x, v.y, v.z, v.w};
    for (int i = 0; i < 4; ++i) {
      bf16_t h = (bf16_t)vv[i];
      sXh[o + i] = h;
      sXl[o + i] = (bf16_t)(vv[i] - (float)h);
    }
  }

  floatx4 acc1[8], acc2[8];
  for (int i = 0; i < 8; ++i) { acc1[i] = {}; acc2[i] = {}; }

  __syncthreads();
#pragma unroll
  for (int ph = 0; ph < 8; ++ph) {
    if (ph < 7) issueW((ph + 1) & 1, ph + 1);
    const bf16_t* wb = sW[ph & 1];
    const int kq = ph & 3;
    floatx4* acc = (ph < 4) ? acc1 : acc2;
    const int ao = (wave * 16 + c15) * 132 + kq * 32 + q * 8;
    bf16x8 ah = *(const bf16x8u*)(sXh + ao);
    bf16x8 al = *(const bf16x8u*)(sXl + ao);
    for (int nt = 0; nt < 8; ++nt) {
      const int bo = (nt * 16 + c15) * 40 + q * 8;
      bf16x8 bh = *(const bf16x8*)(wb + bo);
      bf16x8 bl = *(const bf16x8*)(wb + 128 * 40 + bo);
      acc[nt] = mfma16_bf16(ah, bh, acc[nt]);
      acc[nt] = mfma16_bf16(ah, bl, acc[nt]);
      acc[nt] = mfma16_bf16(al, bh, acc[nt]);
    }
    if (ph == 3) {
      for (int nt = 0; nt < 8; ++nt)
        for (int r = 0; r < 4; ++r) {
          float h = fmaxf(acc1[nt][r] + b1v[nt], 0.f);
          bf16_t hh = (bf16_t)h;
          int o = (wave * 16 + q * 4 + r) * 132 + nt * 16 + c15;
          sXh[o] = hh;
          sXl[o] = (bf16_t)(h - (float)hh);
        }
    }
    __syncthreads();
  }

  for (int nt = 0; nt < 8; ++nt)
    for (int r = 0; r < 4; ++r) {
      float kv = acc2[nt][r] + b2v[nt];
      bf16_t kh = (bf16_t)kv;
      int o = (wave * 16 + q * 4 + r) * 132 + nt * 16 + c15;
      sXh[o] = kh;
      sXl[o] = (bf16_t)(kv - (float)kh);
    }
  __syncthreads();
  for (int u = 0; u < 4; ++u) {
    int idx = tid + u * 256;
    int r = idx >> 4, c8 = (idx & 15) << 3;
    bf16x8 vh = *(const bf16x8u*)(sXh + r * 132 + c8);
    bf16x8 vl = *(const bf16x8u*)(sXl + r * 132 + c8);
    *(bf16x8*)(Khi + (rowBase + r) * 128 + c8) = vh;
    *(bf16x8*)(Klo + (rowBase + r) * 128 + c8) = vl;
  }
}

// ---------------------------------------------------------------------------
// MLP-V: pure f16 (R2-proven numerics), dbuf phases; emits V^T (f16).
// ---------------------------------------------------------------------------
__global__ __launch_bounds__(256) void mlp_v_kernel(
    const float* __restrict__ X, const float* __restrict__ b1,
    const float* __restrict__ b2, const f16_t* __restrict__ W1f,
    const f16_t* __restrict__ W2f, f16_t* __restrict__ Vt) {
  __shared__ __align__(16) f16_t sXf[64 * 136];    // X/H; later V^T [128][68]
  __shared__ __align__(16) f16_t sW[2][128 * 40];

  const int tid = threadIdx.x, lane = tid & 63, wave = tid >> 6;
  const int q = lane >> 4, c15 = lane & 15;
  const size_t rowBase = (size_t)blockIdx.x * 64;

  int goff[3];
  for (int a = 0; a < 3; ++a) {
    int o = (wave + 4 * a) * 1024 + lane * 16;
    int row = o / 80, rem = o % 80;
    goff[a] = row * 256 + (rem < 64 ? rem : 0);
  }
  auto issueV = [&](int buf, int ph) {
    const f16_t* Wp = (ph < 4) ? W1f : W2f;
    const char* base = (const char*)Wp + (ph & 3) * 64;
    for (int a = 0; a < 3; ++a) {
      int j = wave + 4 * a;
      if (j < 10) async_ld16((char*)sW[buf] + j * 1024 + lane * 16, base + goff[a]);
    }
  };

  issueV(0, 0);

  float b1v[8], bvv[2][4];
  for (int nt = 0; nt < 8; ++nt) b1v[nt] = b1[nt * 16 + c15];
  for (int mt = 0; mt < 2; ++mt)
    for (int r = 0; r < 4; ++r)
      bvv[mt][r] = b2[(wave * 2 + mt) * 16 + q * 4 + r];

  for (int u = 0; u < 8; ++u) {
    int idx = tid + u * 256;
    int r = idx >> 5, c4 = (idx & 31) << 2;
    float4 v = *(const float4*)(X + (rowBase + r) * 128 + c4);
    int o = r * 136 + c4;
    sXf[o + 0] = (f16_t)v.x; sXf[o + 1] = (f16_t)v.y;
    sXf[o + 2] = (f16_t)v.z; sXf[o + 3] = (f16_t)v.w;
  }

  floatx4 acc1[8], acc2[2][4];
  for (int i = 0; i < 8; ++i) acc1[i] = {};
  for (int i = 0; i < 2; ++i) for (int j = 0; j < 4; ++j) acc2[i][j] = {};

  __syncthreads();
#pragma unroll
  for (int ph = 0; ph < 8; ++ph) {
    if (ph < 7) issueV((ph + 1) & 1, ph + 1);
    const f16_t* wb = sW[ph & 1];
    const int kq = ph & 3;
    if (ph < 4) {
      f16x8 a = *(const f16x8u*)(sXf + (wave * 16 + c15) * 136 + kq * 32 + q * 8);
      for (int nt = 0; nt < 8; ++nt) {
        f16x8 bb = *(const f16x8*)(wb + (nt * 16 + c15) * 40 + q * 8);
        acc1[nt] = mfma16_f16(a, bb, acc1[nt]);
      }
      if (ph == 3) {
        for (int nt = 0; nt < 8; ++nt)
          for (int r = 0; r < 4; ++r)
            sXf[(wave * 16 + q * 4 + r) * 136 + nt * 16 + c15] =
                (f16_t)fmaxf(acc1[nt][r] + b1v[nt], 0.f);
      }
    } else {
      f16x8 aw0 = *(const f16x8*)(wb + ((wave * 2 + 0) * 16 + c15) * 40 + q * 8);
      f16x8 aw1 = *(const f16x8*)(wb + ((wave * 2 + 1) * 16 + c15) * 40 + q * 8);
      for (int nt = 0; nt < 4; ++nt) {
        f16x8 bh = *(const f16x8u*)(sXf + (nt * 16 + c15) * 136 + kq * 32 + q * 8);
        acc2[0][nt] = mfma16_f16(aw0, bh, acc2[0][nt]);
        acc2[1][nt] = mfma16_f16(aw1, bh, acc2[1][nt]);
      }
    }
    __syncthreads();
  }

  f16_t* sVT = sXf;   // [128][68] f16
  for (int mt = 0; mt < 2; ++mt)
    for (int nt = 0; nt < 4; ++nt)
      for (int r = 0; r < 4; ++r) {
        int c = (wave * 2 + mt) * 16 + q * 4 + r;
        sVT[c * 68 + nt * 16 + c15] = (f16_t)(acc2[mt][nt][r] + bvv[mt][r]);
      }
  __syncthreads();
  const int nh = (int)(rowBase >> 10);
  const int lB = (int)(rowBase & 1023);
  for (int u = 0; u < 4; ++u) {
    int idx = tid + u * 256;
    int c = idx >> 3, l8 = (idx & 7) << 3;
    *(f16x8*)(Vt + ((size_t)nh * 128 + c) * 1024 + lB + l8) =
        *(const f16x8u*)(sVT + c * 68 + l8);
  }
}

// ---------------------------------------------------------------------------
// attn: 512 threads (8 waves, 256 Q-rows), 256 blocks = 1/CU. Triple-buffered
// 32-L tiles, prefetch distance 2, raw s_barrier + s_waitcnt vmcnt(4): the
// newest batch stays in flight across every barrier (no vmcnt(0) drain).
// ---------------------------------------------------------------------------
__global__ __launch_bounds__(512, 2) void attn_kernel(
    const float* __restrict__ Q, const float* __restrict__ t1,
    const float* __restrict__ t2pre, const float* __restrict__ ltau,
    const bf16_t* __restrict__ Khi, const bf16_t* __restrict__ Klo,
    const f16_t* __restrict__ Vt, float* __restrict__ out) {
  __shared__ __align__(16) char sBuf[3][27648];    // [K hi 8704 | K lo 8704 | V 10240]
  __shared__ __align__(16) float sT2[1024];

  const int tid = threadIdx.x, lane = tid & 63, wave = tid >> 6;
  const int h = lane >> 5, l31 = lane & 31;
  const int nh = blockIdx.x & 63;                  // head's 4 T-blocks share XCD slot
  const int tB = (blockIdx.x >> 6) << 8;
  const int n = nh >> 3;
  const int qrow = tB + wave * 32 + l31;
  const float negc2 = -__expf(-ltau[0]) * 1.44269504f;

  // 32 chunk slots (27 real + 5 dups), 4 per wave -> uniform vmcnt accounting
  const char* gp[4]; int ls[4]; int st[4];
  for (int a = 0; a < 4; ++a) {
    int j = wave + 8 * a;
    if (j >= 27) j -= 5;                           // dup-stage chunks 22..26
    if (j < 17) {
      int o = j * 1024 + lane * 16;
      int half = o >= 8704 ? 1 : 0;
      int r2 = o - half * 8704;
      int row = r2 / 272, rem = r2 % 272;
      if (rem >= 256) rem = 0;
      gp[a] = (const char*)(half ? Klo : Khi) + ((size_t)((nh << 10) + row)) * 256 + rem;
      st[a] = 8192; ls[a] = o;
    } else {
      int o = (j - 17) * 1024 + lane * 16;
      int c = o / 80, rem = o % 80;
      if (rem >= 64) rem = 0;
      gp[a] = (const char*)Vt + ((size_t)((nh << 7) + c)) * 2048 + rem;
      st[a] = 64; ls[a] = 17408 + o;
    }
  }
  auto stage = [&](int buf) {
    for (int a = 0; a < 4; ++a) { async_ld16(sBuf[buf] + ls[a], gp[a]); gp[a] += st[a]; }
  };

  // t2 -> LDS (one-time), then Q loads, then prime 2 tile batches
  float2 t2v2 = *(const float2*)(t2pre + (n << 10) + tid * 2);
  const float t1v = t1[(n << 10) + qrow];
  bf16x8 qh[8], ql[8];
  {
    const float* qr = Q + ((size_t)(nh << 10) + qrow) * 128;
    for (int ks = 0; ks < 8; ++ks) {
      const float* p = qr + ks * 16 + h * 8;
      float4 v0 = *(const float4*)p;
      float4 v1 = *(const float4*)(p + 4);
      float vv[8] = {v0.x, v0.y, v0.z, v0.w, v1.x, v1.y, v1.z, v1.w};
      bf16x8 hi, lo;
      for (int j = 0; j < 8; ++j) {
        bf16_t hj = (bf16_t)vv[j];
        hi[j] = hj;
        lo[j] = (bf16_t)(vv[j] - (float)hj);
      }
      qh[ks] = hi;
      ql[ks] = lo;
    }
  }
  stage(0);
  stage(1);
  *(float2*)(sT2 + tid * 2) = t2v2;

  floatx16 O[4];
  for (int i = 0; i < 4; ++i) O[i] = {};
  float ds = 0.f;

  // gate: own stage(0) done (4 newer = stage(1)), t2 ds_write done, then barrier
  asm volatile("s_waitcnt vmcnt(4) lgkmcnt(0)" ::: "memory");
  __builtin_amdgcn_s_barrier();
  asm volatile("" ::: "memory");

  for (int it = 0; it < 32; ++it) {
    if (it < 30) stage((it + 2) % 3);
    const char* kb = sBuf[it % 3];
    const char* vb = kb + 17408;

    floatx16 S = {};
    for (int ks = 0; ks < 8; ++ks) {
      const int bo = l31 * 272 + ks * 32 + h * 16;
      bf16x8 kh_ = *(const bf16x8*)(kb + bo);
      bf16x8 kl_ = *(const bf16x8*)(kb + 8704 + bo);
      S = mfma32_bf16(kh_, qh[ks], S);
      S = mfma32_bf16(kl_, qh[ks], S);
      S = mfma32_bf16(kh_, ql[ks], S);
    }

    const float* t2b = sT2 + it * 32 + h * 4;
    for (int t = 0; t < 4; ++t) {
      float4 tv4 = *(const float4*)(t2b + t * 8);
      float tv[4] = {tv4.x, tv4.y, tv4.z, tv4.w};
      f16x4 pb;
      for (int j = 0; j < 4; ++j) {
        float s = S[4 * t + j];
        float e = fast_exp2(s * s * negc2);
        bool m = (t1v >= tv[j]);
        ds += m ? e : 1.f;
        pb[j] = (f16_t)(m ? e : 0.f);
      }
      for (int ct = 0; ct < 4; ++ct) {
        f16x4 va = *(const f16x4*)(vb + (ct * 32 + l31) * 80 + t * 16 + h * 8);
        O[ct] = mfma32x8_f16(va, pb, O[ct]);
      }
    }

    // retire the distance-2-old batch only; newest stays in flight across barrier
    if (it < 30) {
      asm volatile("s_waitcnt vmcnt(4)" ::: "memory");
    } else if (it == 30) {
      asm volatile("s_waitcnt vmcnt(0)" ::: "memory");
    }
    if (it < 31) {
      asm volatile("" ::: "memory");
      __builtin_amdgcn_s_barrier();
      asm volatile("" ::: "memory");
    }
  }

  ds += __shfl_xor(ds, 32);
  const float inv = 1.f / ds;
  float* orow = out + ((size_t)(nh << 10) + qrow) * 128;
  for (int ct = 0; ct < 4; ++ct)
    for (int t = 0; t < 4; ++t) {
      int c = ct * 32 + 8 * t + 4 * h;
      float4 v = {O[ct][4 * t + 0] * inv, O[ct][4 * t + 1] * inv,
                  O[ct][4 * t + 2] * inv, O[ct][4 * t + 3] * inv};
      *(float4*)(orow + c) = v;
    }
}

extern "C" void kernel_launch(void* const* d_in, const int* in_sizes, int n_in,
                              void* d_out, int out_size, void* d_ws, size_t ws_size,
                              hipStream_t stream) {
  const float* X   = (const float*)d_in[0];
  const float* t1  = (const float*)d_in[1];
  const float* Q   = (const float*)d_in[2];
  const float* Wk1 = (const float*)d_in[3];
  const float* bk1 = (const float*)d_in[4];
  const float* Wk2 = (const float*)d_in[5];
  const float* bk2 = (const float*)d_in[6];
  const float* Wv1 = (const float*)d_in[7];
  const float* bv1 = (const float*)d_in[8];
  const float* Wv2 = (const float*)d_in[9];
  const float* bv2 = (const float*)d_in[10];
  const float* log_tau = (const float*)d_in[11];
  float* out = (float*)d_out;

  const size_t E = (size_t)64 * 1024 * 128;
  bf16_t* Khi = (bf16_t*)d_ws;
  bf16_t* Klo = Khi + E;
  f16_t*  Vt  = (f16_t*)(Klo + E);
  bf16_t* W1p = (bf16_t*)((char*)d_ws + 3 * E * 2);
  bf16_t* W2p = W1p + 32768;
  f16_t*  W3f = (f16_t*)(W2p + 32768);
  f16_t*  W4f = W3f + 16384;
  float*  t2pre = (float*)(W4f + 16384);

  prep_kernel<<<48, 256, 0, stream>>>(Wk1, Wk2, Wv1, Wv2, X, W1p, W2p, W3f, W4f, t2pre);
  mlp_k_kernel<<<1024, 256, 0, stream>>>(X, bk1, bk2, W1p, W2p, Khi, Klo);
  mlp_v_kernel<<<1024, 256, 0, stream>>>(X, bv1, bv2, W3f, W4f, Vt);
  attn_kernel<<<256, 512, 0, stream>>>(Q, t1, t2pre, log_tau, Khi, Klo, Vt, out);
}